// Round 3
// baseline (156.724 us; speedup 1.0000x reference)
//
#include <hip/hip_runtime.h>

#define N_ROWS 131072
#define DIM 64
#define KCODES 512
#define RPB 128     // rows per block
#define CHUNK 64    // codes per LDS chunk
#define XPAD 68
#define WPAD 68

// ws layout (4-byte words): [0] loss_sum (float), [1..513) counts (uint[512])

// fp32 square with an optimization barrier so hipcc (-ffp-contract=fast)
// cannot fuse the multiply into the following add: numpy squares elementwise
// (rounded) BEFORE summing, so we must round the square.
__device__ __forceinline__ float sqr_nf(float x) {
    float s = x * x;
    asm("" : "+v"(s));
    return s;
}

// numpy pairwise_sum semantics for sum(p[d]^2, d=0..63):
// r[j] = (((((((p[j]^2+p[j+8]^2)+p[j+16]^2)+...)+p[j+56]^2,  j=0..7
// res  = ((r0+r1)+(r2+r3))+((r4+r5)+(r6+r7))
__device__ __forceinline__ float np_sumsq64(const float* p) {
    float r[8];
    {
        float4 a = *reinterpret_cast<const float4*>(p);
        float4 b = *reinterpret_cast<const float4*>(p + 4);
        r[0] = sqr_nf(a.x); r[1] = sqr_nf(a.y); r[2] = sqr_nf(a.z); r[3] = sqr_nf(a.w);
        r[4] = sqr_nf(b.x); r[5] = sqr_nf(b.y); r[6] = sqr_nf(b.z); r[7] = sqr_nf(b.w);
    }
#pragma unroll
    for (int i = 8; i < 64; i += 8) {
        float4 a = *reinterpret_cast<const float4*>(p + i);
        float4 b = *reinterpret_cast<const float4*>(p + i + 4);
        r[0] += sqr_nf(a.x); r[1] += sqr_nf(a.y); r[2] += sqr_nf(a.z); r[3] += sqr_nf(a.w);
        r[4] += sqr_nf(b.x); r[5] += sqr_nf(b.y); r[6] += sqr_nf(b.z); r[7] += sqr_nf(b.w);
    }
    return ((r[0] + r[1]) + (r[2] + r[3])) + ((r[4] + r[5]) + (r[6] + r[7]));
}

__global__ __launch_bounds__(256) void vq_main_k(
    const float* __restrict__ X, const float* __restrict__ W,
    float* __restrict__ out_q, float* __restrict__ out_idx,
    float* __restrict__ loss_sum, unsigned* __restrict__ counts) {
    __shared__ float Xs[RPB][XPAD];
    __shared__ float Ws[CHUNK][WPAD];
    __shared__ float wns[CHUNK];
    __shared__ float As[RPB];
    __shared__ int idx_s[RPB];
    __shared__ float lred[4];

    const int tid = threadIdx.x;
    const long base = (long)blockIdx.x * RPB;

    // stage X tile: 128 rows x 64 f32
#pragma unroll
    for (int i = 0; i < 8; ++i) {
        int f = i * 256 + tid;
        int r = f >> 4, c4 = f & 15;
        float4 v = reinterpret_cast<const float4*>(X)[(base + r) * 16 + c4];
        *reinterpret_cast<float4*>(&Xs[r][c4 * 4]) = v;
    }
    __syncthreads();
    // A_n = np.sum(x**2) per row, numpy pairwise order
    if (tid < RPB) As[tid] = np_sumsq64(&Xs[tid][0]);
    __syncthreads();

    const int row_t = tid >> 3;   // 0..31
    const int code_t = tid & 7;   // 0..7
    float Ar[4];
#pragma unroll
    for (int r = 0; r < 4; ++r) Ar[r] = As[row_t + 32 * r];

    float best[4];
    int bidx[4];
#pragma unroll
    for (int r = 0; r < 4; ++r) { best[r] = 3e38f; bidx[r] = 0; }

    for (int ch = 0; ch < KCODES / CHUNK; ++ch) {
        __syncthreads();  // previous chunk fully consumed
#pragma unroll
        for (int i = 0; i < 4; ++i) {
            int f = i * 256 + tid;
            int r = f >> 4, c4 = f & 15;
            float4 v = reinterpret_cast<const float4*>(W)[(ch * CHUNK + r) * 16 + c4];
            *reinterpret_cast<float4*>(&Ws[r][c4 * 4]) = v;
        }
        __syncthreads();
        // b_k = np.sum(w**2) per code, numpy pairwise order
        if (tid < CHUNK) wns[tid] = np_sumsq64(&Ws[tid][0]);
        __syncthreads();

        // C = x . w : single sequential fp32 FMA chain over d ascending
        // (matches BLAS sgemm microkernel accumulation semantics)
        float acc[4][8];
#pragma unroll
        for (int r = 0; r < 4; ++r)
#pragma unroll
            for (int c = 0; c < 8; ++c) acc[r][c] = 0.f;

#pragma unroll 2
        for (int d0 = 0; d0 < DIM; d0 += 4) {
            float4 xv[4], wv[8];
#pragma unroll
            for (int r = 0; r < 4; ++r)
                xv[r] = *reinterpret_cast<const float4*>(&Xs[row_t + 32 * r][d0]);
#pragma unroll
            for (int c = 0; c < 8; ++c)
                wv[c] = *reinterpret_cast<const float4*>(&Ws[code_t + 8 * c][d0]);
#pragma unroll
            for (int r = 0; r < 4; ++r)
#pragma unroll
                for (int c = 0; c < 8; ++c) {
                    acc[r][c] = fmaf(xv[r].x, wv[c].x, acc[r][c]);
                    acc[r][c] = fmaf(xv[r].y, wv[c].y, acc[r][c]);
                    acc[r][c] = fmaf(xv[r].z, wv[c].z, acc[r][c]);
                    acc[r][c] = fmaf(xv[r].w, wv[c].w, acc[r][c]);
                }
        }

        // D = fl( fl(A + b_k) - 2*C ); fold argmin, k ascending per thread,
        // strict < keeps first (numpy first-index tie semantics)
#pragma unroll
        for (int c = 0; c < 8; ++c) {
            int k = ch * CHUNK + code_t + 8 * c;
            float wn = wns[code_t + 8 * c];
#pragma unroll
            for (int r = 0; r < 4; ++r) {
                float u = Ar[r] + wn;          // rounds like numpy's (A + b)
                float s = u - 2.0f * acc[r][c]; // 2*C exact, one rounded subtract
                if (s < best[r]) { best[r] = s; bidx[r] = k; }
            }
        }
    }

    // butterfly merge across the 8 code_t lanes; exact ties -> smaller index
#pragma unroll
    for (int st = 1; st < 8; st <<= 1) {
#pragma unroll
        for (int r = 0; r < 4; ++r) {
            float ob = __shfl_xor(best[r], st);
            int oi = __shfl_xor(bidx[r], st);
            if (ob < best[r] || (ob == best[r] && oi < bidx[r])) {
                best[r] = ob; bidx[r] = oi;
            }
        }
    }

    if (code_t == 0) {
#pragma unroll
        for (int r = 0; r < 4; ++r) {
            int row = row_t + 32 * r;
            idx_s[row] = bidx[r];
            out_idx[base + row] = (float)bidx[r];
        }
    }
    __syncthreads();

    // quantized_st + loss partials
    float ls = 0.f;
#pragma unroll 4
    for (int i = 0; i < 32; ++i) {
        int f = i * 256 + tid;
        int r = f >> 6, d = f & 63;
        int k = idx_s[r];
        float x = Xs[r][d];
        float q = W[k * DIM + d];
        float diff = q - x;
        out_q[(base + r) * DIM + d] = x + diff;  // inputs + (quantized - inputs)
        ls += diff * diff;
    }
#pragma unroll
    for (int st = 1; st < 64; st <<= 1) ls += __shfl_xor(ls, st);
    if ((tid & 63) == 0) lred[tid >> 6] = ls;
    __syncthreads();
    if (tid == 0) atomicAdd(loss_sum, lred[0] + lred[1] + lred[2] + lred[3]);
    if (tid < RPB) atomicAdd(&counts[idx_s[tid]], 1u);
}

__global__ __launch_bounds__(512) void vq_finalize_k(
    const float* __restrict__ loss_sum, const unsigned* __restrict__ counts,
    float* __restrict__ out_loss, float* __restrict__ out_perp) {
    __shared__ float red[512];
    int t = threadIdx.x;
    float p = (float)counts[t] * (1.0f / (float)N_ROWS);
    red[t] = p * logf(p + 1e-10f);
    __syncthreads();
    for (int off = 256; off; off >>= 1) {
        if (t < off) red[t] += red[t + off];
        __syncthreads();
    }
    if (t == 0) {
        *out_perp = expf(-red[0]);
        float m = *loss_sum / (float)(N_ROWS * DIM);
        *out_loss = m + 0.25f * m;
    }
}

extern "C" void kernel_launch(void* const* d_in, const int* in_sizes, int n_in,
                              void* d_out, int out_size, void* d_ws, size_t ws_size,
                              hipStream_t stream) {
    const float* X = (const float*)d_in[0];
    const float* W = (const float*)d_in[1];

    float* out = (float*)d_out;
    float* out_loss = out;                           // [0]
    float* out_q = out + 1;                          // [1 .. 1+N*D)
    float* out_perp = out + 1 + (long)N_ROWS * DIM;  // loss|q|perp|idx
    float* out_idx = out + 2 + (long)N_ROWS * DIM;

    float* loss_sum = (float*)d_ws;
    unsigned* counts = (unsigned*)d_ws + 1;

    hipMemsetAsync(d_ws, 0, 4 + KCODES * 4, stream);
    vq_main_k<<<N_ROWS / RPB, 256, 0, stream>>>(X, W, out_q, out_idx,
                                                loss_sum, counts);
    vq_finalize_k<<<1, 512, 0, stream>>>(loss_sum, counts, out_loss, out_perp);
}